// Round 17
// baseline (123.984 us; speedup 1.0000x reference)
//
#include <hip/hip_runtime.h>
#include <hip/hip_bf16.h>

// BlockAttention: paged KV-cache prefill attention, block-causal mask.
// B=4, LQ=512, HQ=16, HKV=8, D=128, CTX=2048, LK=2560.
// R1: XCD-aware block index. R2: swizzled K/V LDS, dbuf, 1 barrier/tile.
// R3: swapped QK^T, in-register softmax, zero-shuffle PV, defer-max.
// R9/R13: producer/consumer split + vf prefetch (best: 71.3/104.6).
// R15 (FAILED, reverted): 2 blocks/CU.
// R16: kernel is LDS-BW-bound (model: 83% DS busy; 128 b128 frag reads
//      /CU/tile is 4x redundancy). Fix: 64q-rows/wave x kv-half.
//      4 C-waves = (head, kvh); each 64q x 32kv -> 16 reads/wave/tile
//      (64/CU, HALF). Fragment amortized over 4 q-subtiles. MFMA count
//      unchanged. R12-verified algebra: pk32 V slots, pa direct pack,
//      kvh-pair merge via 64KB LDS overlay. Producer = R12 verbatim.

#define B_    4
#define LQ_   512
#define HQ_   16
#define HKV_  8
#define D_    128
#define BLKSZ_ 256
#define BPS_  8
#define CTX_  2048
#define DIFFB_ 128
#define KT_   64
#define SCALE_ 0.08838834764831845f

typedef __attribute__((ext_vector_type(4))) float f32x4;
typedef __attribute__((ext_vector_type(8))) short bf16x8;
typedef __attribute__((ext_vector_type(2))) unsigned u32x2;

__device__ __forceinline__ unsigned cvt_pk2(float a, float b) {
  union { __hip_bfloat162 h; unsigned u; } x;
  x.h = __float22bfloat162_rn(float2{a, b});
  return x.u;
}
union bf8u { bf16x8 v; unsigned u[4]; };

// ---- K tile swizzle (units: shorts), 16B-chunk XOR ----
__device__ __forceinline__ int kidx(int kv, int d) {
  return kv * 128 + ((((d >> 3) ^ kv) & 15) << 3) + (d & 7);
}
// ---- V^T tile swizzle; p is the PHYSICAL (k-label) kv slot ----
__device__ __forceinline__ int vidx(int d, int p) {
  return d * 64 + ((((p >> 3) ^ d ^ (d >> 3)) & 7) << 3) + (p & 7);
}
// kv -> phys k-label within a 32-half: [4][3:2][1:0] -> [3:2][4][1:0]
__device__ __forceinline__ int pk32(int w) {
  return (((w >> 2) & 3) << 3) | (((w >> 4) & 1) << 2) | (w & 3);
}

__global__ __launch_bounds__(512, 2)
void block_attn_kernel(const float* __restrict__ qg,
                       const float* __restrict__ kcur,
                       const float* __restrict__ vcur,
                       const float* __restrict__ kcache,
                       const float* __restrict__ vcache,
                       const int*   __restrict__ btab,
                       float*       __restrict__ out) {
  // grid 256: blk = qb*32 + b*8 + hkv (qb high bits -> same (b,hkv) per XCD)
  const int blk  = blockIdx.x;
  const int hkv  = blk & 7;
  const int b    = (blk >> 3) & 3;
  const int qb   = blk >> 5;                    // 64-row q tile, 0..7
  const int tid  = threadIdx.x;
  const int lane = tid & 63;
  const int wave = tid >> 6;                    // 0..7
  const int lo   = lane & 15;
  const int hi   = lane >> 4;
  const int nt   = (CTX_ + (qb / 2 + 1) * DIFFB_) / KT_;

  // Kl[2] @0,16384; Vl[2] @32768,49152 (bytes). Merge scratch Os
  // (128 rows x 128 f32 = 64KB) overlays everything after the loop.
  __shared__ __align__(16) char smem[65536];
  __shared__ float ms[8][16], ls[8][16];
  float* Os = (float*)smem;

  if (wave < 4) {
    // ====== CONSUMER: 64 q-rows (one head) x 32-kv half ==============
    const int kvh  = wave & 1;                  // kv half
    const int pair = wave >> 1;                 // head select
    const int hq   = hkv * 2 + pair;
    const int qrow0 = qb * 64;

    // Q fragments: qf[qt][db], 4 q-subtiles x 4 k-chunks (scaled bf16)
    bf16x8 qf[4][4];
#pragma unroll
    for (int qt = 0; qt < 4; ++qt) {
      const float* qr = qg + ((size_t)((b * LQ_ + qrow0 + qt * 16 + lo)) * HQ_ + hq) * D_;
#pragma unroll
      for (int db = 0; db < 4; ++db) {
        const int d0 = db * 32 + hi * 8;
        f32x4 a  = *(const f32x4*)(qr + d0);
        f32x4 c4 = *(const f32x4*)(qr + d0 + 4);
        bf8u f;
        f.u[0] = cvt_pk2(a[0] * SCALE_, a[1] * SCALE_);
        f.u[1] = cvt_pk2(a[2] * SCALE_, a[3] * SCALE_);
        f.u[2] = cvt_pk2(c4[0] * SCALE_, c4[1] * SCALE_);
        f.u[3] = cvt_pk2(c4[2] * SCALE_, c4[3] * SCALE_);
        qf[qt][db] = f.v;
      }
    }

    f32x4 oacc[8][4];                           // [dt][qt]
#pragma unroll
    for (int dt = 0; dt < 8; ++dt)
#pragma unroll
      for (int qt = 0; qt < 4; ++qt) oacc[dt][qt] = (f32x4){0.f, 0.f, 0.f, 0.f};
    float mrow[4] = {-1e30f, -1e30f, -1e30f, -1e30f};
    float lrow[4] = {0.f, 0.f, 0.f, 0.f};

    __syncthreads();   // prologue staging done

    for (int t = 0; t < nt; ++t) {
      const short* Kb = (const short*)(smem + (t & 1) * 16384);
      const short* Vb = (const short*)(smem + 32768 + (t & 1) * 16384);

      // ---- S^T = K Q^T : 8 kf reads, each feeds 4 q-subtiles ----
      f32x4 sacc[4][2];
#pragma unroll
      for (int qt = 0; qt < 4; ++qt) {
        sacc[qt][0] = (f32x4){0.f, 0.f, 0.f, 0.f};
        sacc[qt][1] = (f32x4){0.f, 0.f, 0.f, 0.f};
      }
#pragma unroll
      for (int cs = 0; cs < 2; ++cs) {
#pragma unroll
        for (int db = 0; db < 4; ++db) {
          bf16x8 kf = *(const bf16x8*)&Kb[kidx(kvh * 32 + cs * 16 + lo,
                                               db * 32 + hi * 8)];
#pragma unroll
          for (int qt = 0; qt < 4; ++qt)
            sacc[qt][cs] = __builtin_amdgcn_mfma_f32_16x16x32_bf16(
                kf, qf[qt][db], sacc[qt][cs], 0, 0, 0);
        }
      }

      // ---- in-register online softmax + pa pack, per q-subtile ----
      bf16x8 pa[4];
#pragma unroll
      for (int qt = 0; qt < 4; ++qt) {
        float m0 = fmaxf(fmaxf(sacc[qt][0][0], sacc[qt][0][1]),
                         fmaxf(sacc[qt][0][2], sacc[qt][0][3]));
        float m1 = fmaxf(fmaxf(sacc[qt][1][0], sacc[qt][1][1]),
                         fmaxf(sacc[qt][1][2], sacc[qt][1][3]));
        float mx = fmaxf(m0, m1);
        mx = fmaxf(mx, __shfl_xor(mx, 16));
        mx = fmaxf(mx, __shfl_xor(mx, 32));
        const bool keep = __all(mx - mrow[qt] <= 8.0f);   // defer-max
        const float mnew = keep ? mrow[qt] : fmaxf(mrow[qt], mx);
        float rs = 0.f;
#pragma unroll
        for (int cs = 0; cs < 2; ++cs)
#pragma unroll
          for (int i = 0; i < 4; ++i) {
            const float p = __expf(sacc[qt][cs][i] - mnew);
            sacc[qt][cs][i] = p;
            rs += p;
          }
        rs += __shfl_xor(rs, 16);
        rs += __shfl_xor(rs, 32);
        if (keep) {
          lrow[qt] += rs;
        } else {
          const float sc = __expf(mrow[qt] - mnew);
          lrow[qt] = lrow[qt] * sc + rs;
          mrow[qt] = mnew;
#pragma unroll
          for (int dt = 0; dt < 8; ++dt) oacc[dt][qt] *= sc;
        }
        bf8u p;
        p.u[0] = cvt_pk2(sacc[qt][0][0], sacc[qt][0][1]);
        p.u[1] = cvt_pk2(sacc[qt][0][2], sacc[qt][0][3]);
        p.u[2] = cvt_pk2(sacc[qt][1][0], sacc[qt][1][1]);
        p.u[3] = cvt_pk2(sacc[qt][1][2], sacc[qt][1][3]);
        pa[qt] = p.v;
      }

      // ---- O^T += V^T P^T : 8 vf reads, each feeds 4 q-subtiles ----
#pragma unroll
      for (int dt = 0; dt < 8; ++dt) {
        bf16x8 vf = *(const bf16x8*)&Vb[vidx(dt * 16 + lo, kvh * 32 + hi * 8)];
#pragma unroll
        for (int qt = 0; qt < 4; ++qt)
          oacc[dt][qt] = __builtin_amdgcn_mfma_f32_16x16x32_bf16(
              vf, pa[qt], oacc[dt][qt], 0, 0, 0);
      }

      __syncthreads();   // C: no VMEM in flight; drains lgkm only
    }

    // ---- merge kv-halves: kvh=1 publishes, kvh=0 combines + stores ----
    if (kvh == 1) {
#pragma unroll
      for (int qt = 0; qt < 4; ++qt) {
#pragma unroll
        for (int dt = 0; dt < 8; ++dt)
          *(f32x4*)&Os[(size_t)(pair * 64 + qt * 16 + lo) * 128 + dt * 16 + hi * 4] =
              oacc[dt][qt];
        if (hi == 0) { ms[pair * 4 + qt][lo] = mrow[qt]; ls[pair * 4 + qt][lo] = lrow[qt]; }
      }
    }
    __syncthreads();
    if (kvh == 0) {
#pragma unroll
      for (int qt = 0; qt < 4; ++qt) {
        const float m1 = ms[pair * 4 + qt][lo], l1 = ls[pair * 4 + qt][lo];
        const float mstar = fmaxf(mrow[qt], m1);
        const float a0 = __expf(mrow[qt] - mstar);
        const float a1 = __expf(m1 - mstar);
        const float linv = 1.f / (lrow[qt] * a0 + l1 * a1);
        float* orow = out + ((size_t)(b * LQ_ + qrow0 + qt * 16 + lo) * HQ_ + hq) * D_;
#pragma unroll
        for (int dt = 0; dt < 8; ++dt) {
          f32x4 o1 = *(const f32x4*)&Os[(size_t)(pair * 64 + qt * 16 + lo) * 128 + dt * 16 + hi * 4];
          f32x4 o = (oacc[dt][qt] * a0 + o1 * a1) * linv;
          *(f32x4*)(orow + dt * 16 + hi * 4) = o;
        }
      }
    }
  } else {
    // ========== PRODUCER: stage global -> bf16 -> LDS (R12 verbatim) ===
    const int pid = tid & 255;           // 0..255
    const int cK  = pid >> 4;            // K row base (+16*i), i=0..3
    const int e   = pid & 15;            // K d-chunk (8 floats at e*8)
    const int qd  = pid >> 4;            // V row-quad 0..15
    const int dc  = pid & 15;            // V d-chunk (8 floats at dc*8)
    const int r0v = qd * 4;
    const int d0v = dc * 8;
    const int P0v = (r0v & 32) + pk32(r0v & 31);  // 4 consecutive phys slots
    f32x4 kreg[4][2], vreg[4][2];

    auto issue_loads = [&](int t) {
      const int kbase = t * KT_;         // tile never straddles CTX
      const float *kb_, *vb_;
      if (kbase < CTX_) {
        const int pb = btab[b * BPS_ + (kbase >> 8)];
        const size_t base = ((size_t)(pb * BLKSZ_ + (kbase & 255)) * HKV_ + hkv) * D_;
        kb_ = kcache + base; vb_ = vcache + base;
      } else {
        const size_t base = ((size_t)(b * LQ_ + (kbase - CTX_)) * HKV_ + hkv) * D_;
        kb_ = kcur + base;  vb_ = vcur + base;
      }
      const size_t rs = (size_t)HKV_ * D_;
#pragma unroll
      for (int i = 0; i < 4; ++i) {
        const float* kr = kb_ + (size_t)(cK + 16 * i) * rs + e * 8;
        kreg[i][0] = *(const f32x4*)(kr);
        kreg[i][1] = *(const f32x4*)(kr + 4);
      }
#pragma unroll
      for (int m = 0; m < 4; ++m) {
        const float* vr = vb_ + (size_t)(r0v + m) * rs + d0v;
        vreg[m][0] = *(const f32x4*)(vr);
        vreg[m][1] = *(const f32x4*)(vr + 4);
      }
    };

    auto write_lds = [&](int bsel) {
      short* Kb = (short*)(smem + bsel * 16384);
      short* Vb = (short*)(smem + 32768 + bsel * 16384);
#pragma unroll
      for (int i = 0; i < 4; ++i) {      // one b128 per K row-chunk
        bf8u f;
        f.u[0] = cvt_pk2(kreg[i][0][0], kreg[i][0][1]);
        f.u[1] = cvt_pk2(kreg[i][0][2], kreg[i][0][3]);
        f.u[2] = cvt_pk2(kreg[i][1][0], kreg[i][1][1]);
        f.u[3] = cvt_pk2(kreg[i][1][2], kreg[i][1][3]);
        *(bf16x8*)&Kb[kidx(cK + 16 * i, e * 8)] = f.v;
      }
#pragma unroll
      for (int j = 0; j < 8; ++j) {      // one b64 per d: 4 quad-rows packed
        u32x2 w;
        w[0] = cvt_pk2(vreg[0][j >> 2][j & 3], vreg[1][j >> 2][j & 3]);
        w[1] = cvt_pk2(vreg[2][j >> 2][j & 3], vreg[3][j >> 2][j & 3]);
        *(u32x2*)&Vb[vidx(d0v + j, P0v)] = w;
      }
    };

    issue_loads(0);
    write_lds(0);
    if (nt > 1) issue_loads(1);
    asm volatile("s_waitcnt lgkmcnt(0)" ::: "memory");
    __builtin_amdgcn_s_barrier();

    for (int t = 0; t < nt; ++t) {
      if (t + 1 < nt) write_lds((t + 1) & 1);   // auto vmcnt wait on reg use
      if (t + 2 < nt) issue_loads(t + 2);       // in flight across barrier
      asm volatile("s_waitcnt lgkmcnt(0)" ::: "memory");
      __builtin_amdgcn_s_barrier();
    }
    __builtin_amdgcn_s_barrier();   // matches consumers' merge-publish sync
  }
}

extern "C" void kernel_launch(void* const* d_in, const int* in_sizes, int n_in,
                              void* d_out, int out_size, void* d_ws, size_t ws_size,
                              hipStream_t stream) {
  (void)in_sizes; (void)n_in; (void)out_size; (void)d_ws; (void)ws_size;
  const float* q      = (const float*)d_in[0];
  const float* k      = (const float*)d_in[1];
  const float* v      = (const float*)d_in[2];
  const float* kcache = (const float*)d_in[3];
  const float* vcache = (const float*)d_in[4];
  const int*   btab   = (const int*)d_in[5];
  float* out = (float*)d_out;

  block_attn_kernel<<<dim3(B_ * HKV_ * (LQ_ / 64)), dim3(512), 0, stream>>>(
      q, k, v, kcache, vcache, btab, out);
}

// Round 18
// 77.015 us; speedup vs baseline: 1.6099x; 1.6099x over previous
//
#include <hip/hip_runtime.h>
#include <hip/hip_bf16.h>

// BlockAttention: paged KV-cache prefill attention, block-causal mask.
// B=4, LQ=512, HQ=16, HKV=8, D=128, CTX=2048, LK=2560.
// R1: XCD-aware block index. R2: swizzled K/V LDS, dbuf, 1 barrier/tile.
// R3: swapped QK^T, in-register softmax, zero-shuffle PV.
// R9/R13: producer/consumer split + vf prefetch (ref: 71.3/104.6).
// R16 (FAILED): 64q/wave spilled (280 VGPR demand). Reverted.
// R17: critical-path re-order of the consumer tile (producer identical):
//      kf preload -> QK0 -> QK1 -> vfr issue (reuses kfr regs; latency
//      under softmax) -> SM0 -> PV0 (MFMA, interleaves with SM1's VALU)
//      -> SM1 -> PV1. Defer-max branch removed (always-rescale, sc=1
//      when no new max) so the tile is ONE scheduling region.
//      Predicted chain 1600 -> ~1150 cyc.

#define B_    4
#define LQ_   512
#define HQ_   16
#define HKV_  8
#define D_    128
#define BLKSZ_ 256
#define BPS_  8
#define CTX_  2048
#define DIFFB_ 128
#define KT_   64
#define SCALE_ 0.08838834764831845f

typedef __attribute__((ext_vector_type(4))) float f32x4;
typedef __attribute__((ext_vector_type(8))) short bf16x8;
typedef __attribute__((ext_vector_type(2))) unsigned u32x2;

__device__ __forceinline__ unsigned cvt_pk2(float a, float b) {
  union { __hip_bfloat162 h; unsigned u; } x;
  x.h = __float22bfloat162_rn(float2{a, b});
  return x.u;
}
union bf8u { bf16x8 v; unsigned u[4]; };

// ---- K tile swizzle (units: shorts), 16B-chunk XOR ----
__device__ __forceinline__ int kidx(int kv, int d) {
  return kv * 128 + ((((d >> 3) ^ kv) & 15) << 3) + (d & 7);
}
// ---- V^T tile swizzle; p is the PHYSICAL (k-label) kv slot ----
__device__ __forceinline__ int vidx(int d, int p) {
  return d * 64 + ((((p >> 3) ^ d ^ (d >> 3)) & 7) << 3) + (p & 7);
}
// kv bit-permute: swap bits[5:4] <-> bits[3:2] (involution, keeps [1:0])
__device__ __forceinline__ int pkmap(int kv) {
  return ((kv & 12) << 2) | ((kv & 48) >> 2) | (kv & 3);
}

__global__ __launch_bounds__(512, 2)
void block_attn_kernel(const float* __restrict__ qg,
                       const float* __restrict__ kcur,
                       const float* __restrict__ vcur,
                       const float* __restrict__ kcache,
                       const float* __restrict__ vcache,
                       const int*   __restrict__ btab,
                       float*       __restrict__ out) {
  // grid 256: blk = qb*32 + b*8 + hkv (qb high bits -> same (b,hkv) per XCD)
  const int blk  = blockIdx.x;
  const int hkv  = blk & 7;
  const int b    = (blk >> 3) & 3;
  const int qb   = blk >> 5;                    // 64-row q tile, 0..7
  const int tid  = threadIdx.x;
  const int lane = tid & 63;
  const int wave = tid >> 6;                    // 0..7
  const int lo   = lane & 15;
  const int hi   = lane >> 4;
  const int nt   = (CTX_ + (qb / 2 + 1) * DIFFB_) / KT_;

  __shared__ __align__(16) short Kl[2][KT_ * D_];   // 2 x 16 KiB, swizzled
  __shared__ __align__(16) short Vl[2][D_ * KT_];   // 2 x 16 KiB, V^T perm+swz

  if (wave < 4) {
    // ================= CONSUMER: 32 q-rows x 64 kv ====================
    const int hq    = hkv * 2 + (wave >> 1);
    const int qrow0 = qb * 64 + (wave & 1) * 32;

    // Q fragments for both 16-row subtiles (scaled bf16)
    bf16x8 qf[2][4];
#pragma unroll
    for (int sub = 0; sub < 2; ++sub) {
      const float* qr = qg + ((size_t)((b * LQ_ + qrow0 + sub * 16 + lo)) * HQ_ + hq) * D_;
#pragma unroll
      for (int db = 0; db < 4; ++db) {
        const int d0 = db * 32 + hi * 8;
        f32x4 a  = *(const f32x4*)(qr + d0);
        f32x4 c4 = *(const f32x4*)(qr + d0 + 4);
        bf8u f;
        f.u[0] = cvt_pk2(a[0] * SCALE_, a[1] * SCALE_);
        f.u[1] = cvt_pk2(a[2] * SCALE_, a[3] * SCALE_);
        f.u[2] = cvt_pk2(c4[0] * SCALE_, c4[1] * SCALE_);
        f.u[3] = cvt_pk2(c4[2] * SCALE_, c4[3] * SCALE_);
        qf[sub][db] = f.v;
      }
    }

    f32x4 oacc[2][8];
#pragma unroll
    for (int s = 0; s < 2; ++s)
#pragma unroll
      for (int i = 0; i < 8; ++i) oacc[s][i] = (f32x4){0.f, 0.f, 0.f, 0.f};
    float mrow[2] = {-1e30f, -1e30f}, lrow[2] = {0.f, 0.f};

    __syncthreads();   // prologue staging done

    for (int t = 0; t < nt; ++t) {
      const short* Kb = Kl[t & 1];
      const short* Vb = Vl[t & 1];

      // (1) preload ALL K fragments into registers
      bf16x8 kfr[16];
#pragma unroll
      for (int cs = 0; cs < 4; ++cs)
#pragma unroll
        for (int db = 0; db < 4; ++db)
          kfr[cs * 4 + db] = *(const bf16x8*)&Kb[kidx(cs * 16 + lo, db * 32 + hi * 8)];

      // (2)(3) QK sub0 then sub1 — pure-register MFMA chains
      f32x4 s0[4], s1[4];
#pragma unroll
      for (int cs = 0; cs < 4; ++cs) {
        s0[cs] = (f32x4){0.f, 0.f, 0.f, 0.f};
        s1[cs] = (f32x4){0.f, 0.f, 0.f, 0.f};
      }
#pragma unroll
      for (int cs = 0; cs < 4; ++cs)
#pragma unroll
        for (int db = 0; db < 4; ++db)
          s0[cs] = __builtin_amdgcn_mfma_f32_16x16x32_bf16(kfr[cs * 4 + db], qf[0][db], s0[cs], 0, 0, 0);
#pragma unroll
      for (int cs = 0; cs < 4; ++cs)
#pragma unroll
        for (int db = 0; db < 4; ++db)
          s1[cs] = __builtin_amdgcn_mfma_f32_16x16x32_bf16(kfr[cs * 4 + db], qf[1][db], s1[cs], 0, 0, 0);

      // (4) issue vf loads now (kfr's last use is above -> regs reused);
      //     latency hides under SM0 + SM1
      bf16x8 vfr[16];
#pragma unroll
      for (int ch = 0; ch < 2; ++ch)
#pragma unroll
        for (int dt = 0; dt < 8; ++dt)
          vfr[ch * 8 + dt] = *(const bf16x8*)&Vb[vidx(dt * 16 + lo, hi * 16 + ch * 8)];

      // ---- branchless online softmax (always-rescale; sc==1 if no new max)
      bf16x8 pa[2][2];
      auto SM = [&](f32x4 (&s)[4], int sub) {
        float m0 = fmaxf(fmaxf(s[0][0], s[0][1]), fmaxf(s[0][2], s[0][3]));
        float m1 = fmaxf(fmaxf(s[1][0], s[1][1]), fmaxf(s[1][2], s[1][3]));
        float m2 = fmaxf(fmaxf(s[2][0], s[2][1]), fmaxf(s[2][2], s[2][3]));
        float m3 = fmaxf(fmaxf(s[3][0], s[3][1]), fmaxf(s[3][2], s[3][3]));
        float mx = fmaxf(fmaxf(m0, m1), fmaxf(m2, m3));
        mx = fmaxf(mx, __shfl_xor(mx, 16));
        mx = fmaxf(mx, __shfl_xor(mx, 32));
        const float mnew = fmaxf(mrow[sub], mx);
        const float sc = __expf(mrow[sub] - mnew);   // ==1 when mrow>=mx
        mrow[sub] = mnew;
        float rs = 0.f;
#pragma unroll
        for (int cs = 0; cs < 4; ++cs)
#pragma unroll
          for (int i = 0; i < 4; ++i) {
            const float p = __expf(s[cs][i] - mnew);
            s[cs][i] = p;
            rs += p;
          }
        rs += __shfl_xor(rs, 16);
        rs += __shfl_xor(rs, 32);
        lrow[sub] = lrow[sub] * sc + rs;
#pragma unroll
        for (int dt = 0; dt < 8; ++dt) oacc[sub][dt] *= sc;
#pragma unroll
        for (int ch = 0; ch < 2; ++ch) {
          bf8u p;
          p.u[0] = cvt_pk2(s[2 * ch][0],     s[2 * ch][1]);
          p.u[1] = cvt_pk2(s[2 * ch][2],     s[2 * ch][3]);
          p.u[2] = cvt_pk2(s[2 * ch + 1][0], s[2 * ch + 1][1]);
          p.u[3] = cvt_pk2(s[2 * ch + 1][2], s[2 * ch + 1][3]);
          pa[sub][ch] = p.v;
        }
      };

      // (5) SM0
      SM(s0, 0);
      // (6) PV sub0 — MFMAs interleave with SM1's VALU (same sched region)
#pragma unroll
      for (int ch = 0; ch < 2; ++ch)
#pragma unroll
        for (int dt = 0; dt < 8; ++dt)
          oacc[0][dt] = __builtin_amdgcn_mfma_f32_16x16x32_bf16(vfr[ch * 8 + dt], pa[0][ch], oacc[0][dt], 0, 0, 0);
      // (7) SM1
      SM(s1, 1);
      // (8) PV sub1
#pragma unroll
      for (int ch = 0; ch < 2; ++ch)
#pragma unroll
        for (int dt = 0; dt < 8; ++dt)
          oacc[1][dt] = __builtin_amdgcn_mfma_f32_16x16x32_bf16(vfr[ch * 8 + dt], pa[1][ch], oacc[1][dt], 0, 0, 0);

      __syncthreads();   // C: no VMEM in flight; drains lgkm only
    }

    // ---- epilogue: direct store ----
#pragma unroll
    for (int sub = 0; sub < 2; ++sub) {
      const float inv = 1.f / lrow[sub];
      float* orow = out + ((size_t)(b * LQ_ + qrow0 + sub * 16 + lo) * HQ_ + hq) * D_;
#pragma unroll
      for (int dt = 0; dt < 8; ++dt) {
        f32x4 o4 = oacc[sub][dt] * inv;
        *(f32x4*)(orow + dt * 16 + hi * 4) = o4;
      }
    }
  } else {
    // ================= PRODUCER: stage global -> bf16 -> LDS (R9) =====
    const int pid = tid & 255;           // 0..255
    const int cK  = pid >> 4;            // K row base (+16*i), i=0..3
    const int e   = pid & 15;            // K d-chunk (8 floats at e*8)
    const int qd  = pid >> 4;            // V row-quad 0..15
    const int dc  = pid & 15;            // V d-chunk (8 floats at dc*8)
    const int r0v = qd * 4;
    const int d0v = dc * 8;
    const int P0v = pkmap(r0v);          // rows r0v..r0v+3 -> P0v..P0v+3
    f32x4 kreg[4][2], vreg[4][2];

    auto issue_loads = [&](int t) {
      const int kbase = t * KT_;         // tile never straddles CTX
      const float *kb_, *vb_;
      if (kbase < CTX_) {
        const int pb = btab[b * BPS_ + (kbase >> 8)];
        const size_t base = ((size_t)(pb * BLKSZ_ + (kbase & 255)) * HKV_ + hkv) * D_;
        kb_ = kcache + base; vb_ = vcache + base;
      } else {
        const size_t base = ((size_t)(b * LQ_ + (kbase - CTX_)) * HKV_ + hkv) * D_;
        kb_ = kcur + base;  vb_ = vcur + base;
      }
      const size_t rs = (size_t)HKV_ * D_;
#pragma unroll
      for (int i = 0; i < 4; ++i) {
        const float* kr = kb_ + (size_t)(cK + 16 * i) * rs + e * 8;
        kreg[i][0] = *(const f32x4*)(kr);
        kreg[i][1] = *(const f32x4*)(kr + 4);
      }
#pragma unroll
      for (int m = 0; m < 4; ++m) {
        const float* vr = vb_ + (size_t)(r0v + m) * rs + d0v;
        vreg[m][0] = *(const f32x4*)(vr);
        vreg[m][1] = *(const f32x4*)(vr + 4);
      }
    };

    auto write_lds = [&](int bsel) {
      short* Kb = Kl[bsel];
      short* Vb = Vl[bsel];
#pragma unroll
      for (int i = 0; i < 4; ++i) {      // one b128 per K row-chunk
        bf8u f;
        f.u[0] = cvt_pk2(kreg[i][0][0], kreg[i][0][1]);
        f.u[1] = cvt_pk2(kreg[i][0][2], kreg[i][0][3]);
        f.u[2] = cvt_pk2(kreg[i][1][0], kreg[i][1][1]);
        f.u[3] = cvt_pk2(kreg[i][1][2], kreg[i][1][3]);
        *(bf16x8*)&Kb[kidx(cK + 16 * i, e * 8)] = f.v;
      }
#pragma unroll
      for (int j = 0; j < 8; ++j) {      // one b64 per d: 4 quad-rows packed
        u32x2 w;
        w[0] = cvt_pk2(vreg[0][j >> 2][j & 3], vreg[1][j >> 2][j & 3]);
        w[1] = cvt_pk2(vreg[2][j >> 2][j & 3], vreg[3][j >> 2][j & 3]);
        *(u32x2*)&Vb[vidx(d0v + j, P0v)] = w;
      }
    };

    issue_loads(0);
    write_lds(0);
    if (nt > 1) issue_loads(1);
    asm volatile("s_waitcnt lgkmcnt(0)" ::: "memory");
    __builtin_amdgcn_s_barrier();

    for (int t = 0; t < nt; ++t) {
      if (t + 1 < nt) write_lds((t + 1) & 1);   // auto vmcnt wait on reg use
      if (t + 2 < nt) issue_loads(t + 2);       // in flight across barrier
      asm volatile("s_waitcnt lgkmcnt(0)" ::: "memory");
      __builtin_amdgcn_s_barrier();
    }
  }
}

extern "C" void kernel_launch(void* const* d_in, const int* in_sizes, int n_in,
                              void* d_out, int out_size, void* d_ws, size_t ws_size,
                              hipStream_t stream) {
  (void)in_sizes; (void)n_in; (void)out_size; (void)d_ws; (void)ws_size;
  const float* q      = (const float*)d_in[0];
  const float* k      = (const float*)d_in[1];
  const float* v      = (const float*)d_in[2];
  const float* kcache = (const float*)d_in[3];
  const float* vcache = (const float*)d_in[4];
  const int*   btab   = (const int*)d_in[5];
  float* out = (float*)d_out;

  block_attn_kernel<<<dim3(B_ * HKV_ * (LQ_ / 64)), dim3(512), 0, stream>>>(
      q, k, v, kcache, vcache, btab, out);
}